// Round 17
// baseline (225.326 us; speedup 1.0000x reference)
//
#include <hip/hip_runtime.h>

#define B_ 4
#define S_ 2048
#define D_ 1024
#define H_ 16
#define HD_ 64

typedef __attribute__((ext_vector_type(8))) short bf16x8;
typedef __attribute__((ext_vector_type(4))) float f32x4;
typedef __attribute__((ext_vector_type(4))) unsigned u32x4;

__device__ __forceinline__ short f2bf(float f) {
  unsigned u = __builtin_bit_cast(unsigned, f);
  u += 0x7fffu + ((u >> 16) & 1u);   // RNE
  return (short)(u >> 16);
}

// HW packed f32x2 -> bf16x2 (RNE); no builtin on gfx950 -> inline asm (T12)
__device__ __forceinline__ unsigned cvtpk(float a, float b) {
  unsigned r;
  asm("v_cvt_pk_bf16_f32 %0, %1, %2" : "=v"(r) : "v"(a), "v"(b));
  return r;
}

__device__ __forceinline__ void gload_lds16(const void* g, void* l) {
  __builtin_amdgcn_global_load_lds((const __attribute__((address_space(1))) void*)g,
                                   (__attribute__((address_space(3))) void*)l, 16, 0, 0);
}

// swizzled LDS bf16x8 read from a [rows][64] bf16 tile (128B rows, T2 XOR swizzle)
__device__ __forceinline__ bf16x8 ldsw8(const short* base, int row, int colb) {
  const int off = (row * 128 + colb) ^ ((row & 7) << 4);
  return *(const bf16x8*)((const char*)base + off);
}

// pair-row swizzle for 64B-row bf16 tiles ([rows][32 shorts]): logical (row, cbyte)
// -> byte offset. Per-16-lane slot = ((row&1)*4+lq) ^ ((row>>1)&7): all 8 slots x2 = free.
__device__ __forceinline__ int bpr_off(int row, int cbyte) {
  return ((row >> 1) << 7) + ((((row & 1) << 6) + cbyte) ^ (((row >> 1) & 7) << 4));
}

#define MFMA16(a, b, c) __builtin_amdgcn_mfma_f32_16x16x32_bf16((a), (b), (c), 0, 0, 0)
#define PBAR()   asm volatile("s_barrier" ::: "memory")
#define LGKM0()  do { asm volatile("s_waitcnt lgkmcnt(0)" ::: "memory"); \
                      __builtin_amdgcn_sched_barrier(0); } while (0)

// ---------------- 4x W [K][N] f32 -> Wt [N][K] bf16, one dispatch ----------------
__global__ void transpose_cast_w4(const float* __restrict__ W0, const float* __restrict__ W1,
                                  const float* __restrict__ W2, const float* __restrict__ W3,
                                  short* __restrict__ T0, short* __restrict__ T1,
                                  short* __restrict__ T2, short* __restrict__ T3) {
  __shared__ float tile[32][33];
  const int z = blockIdx.z;
  const float* W = z == 0 ? W0 : z == 1 ? W1 : z == 2 ? W2 : W3;
  short* Wt = z == 0 ? T0 : z == 1 ? T1 : z == 2 ? T2 : T3;
  const int n0 = blockIdx.x * 32, k0 = blockIdx.y * 32;
  const int tx = threadIdx.x, ty = threadIdx.y;  // 32 x 8
  #pragma unroll
  for (int i = ty; i < 32; i += 8)
    tile[i][tx] = W[(size_t)(k0 + i) * 1024 + n0 + tx];
  __syncthreads();
  #pragma unroll
  for (int i = ty; i < 32; i += 8)
    Wt[(size_t)(n0 + i) * 1024 + k0 + tx] = f2bf(tile[tx][i]);
}

// ------ 8-phase 256x256x64 QKV GEMM with FUSED f32->bf16 A (R7 skeleton + R13 reg-stage) ------
// 512 thr = 8 waves (2M x 4N); per-wave 128x64 out (acc[8][4]). LDS 128 KB:
// 2 bufs x {A0,A1,B0,B1} bf16 half-tiles [128][64], T2-XOR-swizzled 128B rows.
// B halves: global_load_lds (R7-proven). A halves: REG-STAGED from f32 source —
//   p0: issue 4x dwordx4 A0(t+1) -> rA0;  p1: issue rA1 + gload B0(t+2);
//   p2: gload B1(t+2) + cvtpk/ds_write rA0 -> lds[o][0] (dead region);
//   p3: cvtpk/ds_write rA1 -> lds[o][1].
// Compiler auto-inserts counted vmcnt before each writeAh's cvtpk (R13-proven).
// Entry wait vmcnt(4): outstanding = 4 B(t+2) gload items; B(t+1)/A(t+1) older/drained.
// Each phase's LGKM0 (before MFMA, before barrier) drains the ds_writes -> visible at t+1.
// z==0: Q out [B][H][S][HD]*qscale; z==1: K out; z==2: V out [B][H][HD][S].
__global__ __launch_bounds__(512, 2) void gemm8(const float* __restrict__ Aq,
                                                const float* __restrict__ Ak,
                                                const float* __restrict__ Av,
                                                const short* __restrict__ Bq,
                                                const short* __restrict__ Bk,
                                                const short* __restrict__ Bv,
                                                short* __restrict__ Oq,
                                                short* __restrict__ Ok,
                                                short* __restrict__ Ov,
                                                float qscale) {
  __shared__ __align__(16) short lds[2][4][8192];   // [buf][A0,A1,B0,B1][16KB]
  const int z = blockIdx.z;
  const float* A = z == 0 ? Aq : z == 1 ? Ak : Av;
  const short* Bt = z == 0 ? Bq : z == 1 ? Bk : Bv;
  short* outb = z == 0 ? Oq : z == 1 ? Ok : Ov;
  const float oscale = (z == 0) ? qscale : 1.0f;

  const int tid = threadIdx.x;
  const int l = tid & 63, w = tid >> 6;
  const int wm = w >> 2, wn = w & 3;                // 2M x 4N waves
  const int l15 = l & 15, lq = l >> 4;
  const int flat = blockIdx.x + (blockIdx.y << 2);  // grid (4, 32, 3)
  const int vid = (flat & 7) * 16 + (flat >> 3);    // XCD-grouped remap
  const int row0 = (vid >> 2) * 256;
  const int col0 = (vid & 3) * 256;

  f32x4 acc[8][4] = {};

  // B half-tile staging: 16KB via global_load_lds, XOR-pre-swizzled source (R7)
  auto stageB = [&](short* dst, int hrow, int kt) {
    #pragma unroll
    for (int j = 0; j < 2; ++j) {
      const int o2 = w * 1024 + j * 8192 + l * 16;
      const int row = o2 >> 7;
      const int sc = (o2 & 127) ^ ((row & 7) << 4);
      gload_lds16((const char*)Bt + ((size_t)(col0 + hrow + row) * 1024 + kt * 64) * 2 + sc,
                  (char*)dst + o2);
    }
  };
  // A half reg-stage: thread covers row tid>>2, 16 f32 at col (tid&3)*16
  const int arow = tid >> 2;
  const int acb = (tid & 3) * 32;                   // byte col in 128B bf16 row
  float4 rA0[4], rA1[4];
  auto loadAh = [&](float4* r, int hrow, int kt) {
    const float4* p = (const float4*)(A + (size_t)(row0 + hrow + arow) * 1024 +
                                      kt * 64 + (tid & 3) * 16);
    r[0] = p[0]; r[1] = p[1]; r[2] = p[2]; r[3] = p[3];
  };
  auto writeAh = [&](const float4* r, short* dst) {
    const u32x4 w0 = {cvtpk(r[0].x, r[0].y), cvtpk(r[0].z, r[0].w),
                      cvtpk(r[1].x, r[1].y), cvtpk(r[1].z, r[1].w)};
    const u32x4 w1 = {cvtpk(r[2].x, r[2].y), cvtpk(r[2].z, r[2].w),
                      cvtpk(r[3].x, r[3].y), cvtpk(r[3].z, r[3].w)};
    *(u32x4*)((char*)dst + ((arow * 128 + acb) ^ ((arow & 7) << 4))) = w0;
    *(u32x4*)((char*)dst + ((arow * 128 + acb + 16) ^ ((arow & 7) << 4))) = w1;
  };

  // prologue: A(0) via regs, B(0)+B(1) via gload; lgkm drain so writes visible at barrier
  loadAh(rA0, 0, 0);
  loadAh(rA1, 128, 0);
  writeAh(rA0, lds[0][0]);
  writeAh(rA1, lds[0][1]);
  stageB(lds[0][2], 0, 0);
  stageB(lds[0][3], 128, 0);
  stageB(lds[1][2], 0, 1);
  stageB(lds[1][3], 128, 1);
  asm volatile("s_waitcnt lgkmcnt(0)" ::: "memory");

  for (int t = 0; t < 16; ++t) {
    const int c = t & 1, o = c ^ 1;
    if (t < 15) asm volatile("s_waitcnt vmcnt(4)" ::: "memory");
    else        asm volatile("s_waitcnt vmcnt(0)" ::: "memory");
    PBAR();

    const short* Ah = lds[c][wm];
    const short* Bh = lds[c][2 + (wn >> 1)];
    const int brow = (wn & 1) * 64;
    bf16x8 bfr[4][2];

    #pragma unroll
    for (int p = 0; p < 4; ++p) {
      // staging first (targets dead since the entry barrier; R7 dead-region proof)
      if (p == 0 && t + 1 < 16) loadAh(rA0, 0, t + 1);
      if (p == 1 && t + 1 < 16) loadAh(rA1, 128, t + 1);
      if (p == 1 && t + 2 < 16) stageB(lds[c][2], 0, t + 2);
      if (p == 2 && t + 2 < 16) stageB(lds[c][3], 128, t + 2);
      if (p == 2 && t + 1 < 16) writeAh(rA0, lds[o][0]);   // auto counted-vmcnt before cvtpk
      if (p == 3 && t + 1 < 16) writeAh(rA1, lds[o][1]);

      if (p == 0) {
        #pragma unroll
        for (int nf = 0; nf < 4; ++nf)
          #pragma unroll
          for (int ks = 0; ks < 2; ++ks)
            bfr[nf][ks] = ldsw8(Bh, brow + nf * 16 + l15, ks * 64 + lq * 16);
      }
      const bf16x8 a00 = ldsw8(Ah, (2 * p) * 16 + l15, lq * 16);
      const bf16x8 a01 = ldsw8(Ah, (2 * p) * 16 + l15, 64 + lq * 16);
      const bf16x8 a10 = ldsw8(Ah, (2 * p + 1) * 16 + l15, lq * 16);
      const bf16x8 a11 = ldsw8(Ah, (2 * p + 1) * 16 + l15, 64 + lq * 16);

      LGKM0();    // drains ds-reads AND this phase's ds_writes before barrier
      __builtin_amdgcn_s_setprio(1);
      #pragma unroll
      for (int nf = 0; nf < 4; ++nf) {
        acc[2 * p][nf]     = MFMA16(a00, bfr[nf][0], acc[2 * p][nf]);
        acc[2 * p][nf]     = MFMA16(a01, bfr[nf][1], acc[2 * p][nf]);
        acc[2 * p + 1][nf] = MFMA16(a10, bfr[nf][0], acc[2 * p + 1][nf]);
        acc[2 * p + 1][nf] = MFMA16(a11, bfr[nf][1], acc[2 * p + 1][nf]);
      }
      __builtin_amdgcn_s_setprio(0);
      PBAR();
    }
  }

  // epilogue: C/D layout col=lane&15, row=(lane>>4)*4+reg
  #pragma unroll
  for (int mf = 0; mf < 8; ++mf) {
    #pragma unroll
    for (int nf = 0; nf < 4; ++nf) {
      #pragma unroll
      for (int r = 0; r < 4; ++r) {
        const int gr = row0 + wm * 128 + mf * 16 + lq * 4 + r;  // m = b*S + s
        const int gc = col0 + wn * 64 + nf * 16 + l15;          // n = h*64 + hd
        const float v = acc[mf][nf][r];
        const int b = gr >> 11, s = gr & 2047;
        const int h = gc >> 6, hd = gc & 63;
        if (z < 2)
          outb[(((size_t)(b * H_ + h)) * S_ + s) * HD_ + hd] = f2bf(v * oscale);
        else
          outb[(((size_t)(b * H_ + h)) * HD_ + hd) * S_ + s] = f2bf(v);
      }
    }
  }
}

// ---------------- O-projection GEMM (R6 proven): f32 out = A_bf16 @ Wot^T + bias ----------------
__global__ __launch_bounds__(256) void gemm_o(const short* __restrict__ A,
                                              const short* __restrict__ Bt,
                                              float* __restrict__ outf,
                                              const float* __restrict__ bias) {
  __shared__ __align__(16) short As[2][128 * 32];
  __shared__ __align__(16) short Bs[2][128 * 32];
  const int tid = threadIdx.x;
  const int l = tid & 63;
  const int w = tid >> 6;
  const int wm = w >> 1, wn = w & 1;
  const int flat = blockIdx.x + (blockIdx.y << 3);
  const int xcd = flat & 7, t = flat >> 3;
  const int row0 = (xcd * 8 + (t & 7)) * 128;
  const int col0 = (t >> 3) * 128;
  const int l15 = l & 15, lq = l >> 4;

  f32x4 acc[4][4] = {};

  auto stage = [&](const short* src, int r0, int k0, short* lds) {
    #pragma unroll
    for (int i = 0; i < 2; i++) {
      const int o = w * 2048 + i * 1024 + l * 16;      // dest byte in 8KB tile
      const int row2 = o >> 7;
      const int ip = (o & 127) ^ ((row2 & 7) << 4);
      const int row = row2 * 2 + (ip >> 6);
      const int cb = ip & 63;
      gload_lds16((const char*)src + ((size_t)(r0 + row) * 1024 + k0) * 2 + cb,
                  (char*)lds + o);
    }
  };

  stage(A, row0, 0, As[0]);
  stage(Bt, col0, 0, Bs[0]);

  for (int kt = 0; kt < 32; ++kt) {
    __syncthreads();
    if (kt + 1 < 32) {
      stage(A, row0, (kt + 1) * 32, As[(kt + 1) & 1]);
      stage(Bt, col0, (kt + 1) * 32, Bs[(kt + 1) & 1]);
    }
    const short* as = As[kt & 1];
    const short* bs = Bs[kt & 1];
    bf16x8 af[4], bfv[4];
    #pragma unroll
    for (int mf = 0; mf < 4; mf++)
      af[mf] = *(const bf16x8*)((const char*)as + bpr_off(wm * 64 + mf * 16 + l15, lq * 16));
    #pragma unroll
    for (int nf = 0; nf < 4; nf++)
      bfv[nf] = *(const bf16x8*)((const char*)bs + bpr_off(wn * 64 + nf * 16 + l15, lq * 16));
    #pragma unroll
    for (int mf = 0; mf < 4; mf++)
      #pragma unroll
      for (int nf = 0; nf < 4; nf++)
        acc[mf][nf] = MFMA16(af[mf], bfv[nf], acc[mf][nf]);
  }

  #pragma unroll
  for (int mf = 0; mf < 4; mf++)
    #pragma unroll
    for (int nf = 0; nf < 4; nf++)
      #pragma unroll
      for (int r = 0; r < 4; r++) {
        const int gr = row0 + wm * 64 + mf * 16 + lq * 4 + r;
        const int gc = col0 + wn * 64 + nf * 16 + l15;
        outf[(size_t)gr * 1024 + gc] = acc[mf][nf][r] + bias[gc];
      }
}

// ---------------- causal flash attention (R12 EXACT, known-pass) ----------------
__global__ __launch_bounds__(256) void attn_kernel(const short* __restrict__ Qh,
                                                   const short* __restrict__ Kh,
                                                   const short* __restrict__ Vtr,
                                                   short* __restrict__ attnout) {
  __shared__ __align__(16) short Ks[2][64 * 64];   // [kv][hd] swizzled
  __shared__ __align__(16) short Vs[2][64 * 64];   // [hd][kv] swizzled
  __shared__ __align__(16) short Ps[4][32 * 64];   // per-wave P[q][kv] swizzled
  const int tid = threadIdx.x, l = tid & 63, w = tid >> 6;
  const int l15 = l & 15, lq = l >> 4;
  const int flat = blockIdx.x;
  const int vid = (flat & 7) * 64 + (flat >> 3);   // 8 bh per XCD (K+V working set ~4MB = L2)
  const int bh = vid >> 3, pairx = vid & 7;
  const int b = bh >> 4, h = bh & 15;
  const size_t base = (size_t)bh * (S_ * HD_);
  const short* Qp = Qh + base;
  const short* Kp = Kh + base;
  const short* Vp = Vtr + base;   // [64][2048]
  short* Pw = (short*)Ps[w];

  for (int pass = 0; pass < 2; ++pass) {
    const int qt = pass ? 15 - pairx : pairx;      // diagonal pairing: total work uniform
    const int q0 = qt * 128;
    const int qw = q0 + w * 32;
    const int nkt = (q0 >> 6) + 2;

    // Q B-fragments (q already pre-scaled by 0.125*log2e in the Q projection)
    bf16x8 qf[2][2];
    #pragma unroll
    for (int qh = 0; qh < 2; qh++)
      #pragma unroll
      for (int ks = 0; ks < 2; ks++)
        qf[qh][ks] = *(const bf16x8*)(Qp + (size_t)(qw + qh * 16 + l15) * 64 + ks * 32 + lq * 8);

    f32x4 oacc[4][2] = {};          // [hd-frag][q-half]: O^T, rows hd, cols q=l15
    float mrow[2] = {-1e30f, -1e30f};
    float lpart[2] = {0.f, 0.f};    // per-lane partial row-sum (reduced only at epilogue)

    auto stage = [&](int kt, int bf) {
      const int k0s = kt << 6;
      #pragma unroll
      for (int i = 0; i < 2; i++) {
        const int o = w * 2048 + i * 1024 + l * 16;          // byte offset in 8KB tile
        const int sw = o ^ (((o >> 7) & 7) << 4);            // inverse-swizzled source (rule 21)
        gload_lds16((const char*)Kp + (size_t)k0s * 128 + sw, (char*)Ks[bf] + o);
        gload_lds16(Vp + (size_t)(o >> 7) * S_ + k0s + ((sw & 127) >> 1), (char*)Vs[bf] + o);
      }
    };

    stage(0, 0);
    __syncthreads();

    for (int kt = 0; kt < nkt; ++kt) {
      const int cur = kt & 1;
      if (kt + 1 < nkt) stage(kt + 1, cur ^ 1);   // prefetch in flight across compute
      const int k0 = kt << 6;

      if (k0 <= qw + 31) {                         // wave-level fully-masked-tile skip
        // --- QK^T swapped: sacc[qh][mf] holds S^T[kv=16mf+4lq+r][q=16qh+l15] ---
        f32x4 sacc[2][4] = {};
        __builtin_amdgcn_s_setprio(1);
        #pragma unroll
        for (int ks = 0; ks < 2; ks++) {
          #pragma unroll
          for (int mf = 0; mf < 4; mf++) {
            const bf16x8 kf = ldsw8(Ks[cur], mf * 16 + l15, ks * 64 + lq * 16);
            #pragma unroll
            for (int qh = 0; qh < 2; qh++)
              sacc[qh][mf] = MFMA16(kf, qf[qh][ks], sacc[qh][mf]);
          }
        }
        __builtin_amdgcn_s_setprio(0);

        // causal mask — only diagonal tiles
        if (k0 + 63 > qw) {
          #pragma unroll
          for (int qh = 0; qh < 2; qh++) {
            const int qg = qw + qh * 16 + l15 - lq * 4;   // kv>q  <=>  k0+16mf+r > qg
            #pragma unroll
            for (int mf = 0; mf < 4; mf++)
              #pragma unroll
              for (int r = 0; r < 4; r++)
                if (k0 + mf * 16 + r > qg) sacc[qh][mf][r] = -1e30f;
          }
        }

        // per-lane local max: balanced tree (v_max3-fusible), no shfl unless rescale fires
        float mxl[2];
        #pragma unroll
        for (int qh = 0; qh < 2; qh++) {
          float t0 = fmaxf(fmaxf(sacc[qh][0][0], sacc[qh][0][1]),
                           fmaxf(sacc[qh][0][2], sacc[qh][0][3]));
          float t1 = fmaxf(fmaxf(sacc[qh][1][0], sacc[qh][1][1]),
                           fmaxf(sacc[qh][1][2], sacc[qh][1][3]));
          float t2 = fmaxf(fmaxf(sacc[qh][2][0], sacc[qh][2][1]),
                           fmaxf(sacc[qh][2][2], sacc[qh][2][3]));
          float t3 = fmaxf(fmaxf(sacc[qh][3][0], sacc[qh][3][1]),
                           fmaxf(sacc[qh][3][2], sacc[qh][3][3]));
          mxl[qh] = fmaxf(fmaxf(t0, t1), fmaxf(t2, t3));
        }

        // defer-max (T13, THR=8 in log2 domain); lane-max trigger == row-max trigger
        const bool need = (mxl[0] > mrow[0] + 8.f) || (mxl[1] > mrow[1] + 8.f);
        if (__any(need)) {
          #pragma unroll
          for (int qh = 0; qh < 2; qh++) {
            float m = fmaxf(mxl[qh], __shfl_xor(mxl[qh], 16));
            m = fmaxf(m, __shfl_xor(m, 32));
            const float mn = fmaxf(mrow[qh], m);
            const float fac = __builtin_amdgcn_exp2f(mrow[qh] - mn);
            mrow[qh] = mn;
            lpart[qh] *= fac;
            #pragma unroll
            for (int mf = 0; mf < 4; mf++) oacc[mf][qh] *= fac;
          }
        }

        // exp2, per-lane sum, HW-packed P -> per-wave LDS (8 x ds_write_b64)
        #pragma unroll
        for (int qh = 0; qh < 2; qh++) {
          float rs = 0.f;
          const int row = qh * 16 + l15;
          #pragma unroll
          for (int mf = 0; mf < 4; mf++) {
            f32x4 p;
            #pragma unroll
            for (int r = 0; r < 4; r++) {
              const float e = __builtin_amdgcn_exp2f(sacc[qh][mf][r] - mrow[qh]);
              p[r] = e;
              rs += e;
            }
            const int off = (row * 128 + mf * 32 + lq * 8) ^ ((row & 7) << 4);
            *(uint2*)((char*)Pw + off) = make_uint2(cvtpk(p[0], p[1]), cvtpk(p[2], p[3]));
          }
          lpart[qh] += rs;
        }

        asm volatile("s_waitcnt lgkmcnt(0)" ::: "memory");
        __builtin_amdgcn_sched_barrier(0);

        // --- PV swapped: oacc[mf][qh] += V^T-frag x P^T-frag ---
        __builtin_amdgcn_s_setprio(1);
        #pragma unroll
        for (int ks = 0; ks < 2; ks++) {
          bf16x8 pb[2];
          #pragma unroll
          for (int qh = 0; qh < 2; qh++) {
            const int row = qh * 16 + l15;
            const int off = (row * 128 + ks * 64 + lq * 16) ^ ((row & 7) << 4);
            pb[qh] = *(const bf16x8*)((const char*)Pw + off);
          }
          #pragma unroll
          for (int mf = 0; mf < 4; mf++) {
            const bf16x8 vf = ldsw8(Vs[cur], mf * 16 + l15, ks * 64 + lq * 16);
            #pragma unroll
            for (int qh = 0; qh < 2; qh++)
              oacc[mf][qh] = MFMA16(vf, pb[qh], oacc[mf][qh]);
          }
        }
        __builtin_amdgcn_s_setprio(0);
      }
      __syncthreads();   // prefetch drained (vmcnt) + all waves done with buf cur
    }

    // epilogue: O^T rows hd=16mf+4lq+r, col q=16qh+l15 -> attnout [B][S][H*HD]
    #pragma unroll
    for (int qh = 0; qh < 2; qh++) {
      float lr = lpart[qh];
      lr += __shfl_xor(lr, 16);
      lr += __shfl_xor(lr, 32);
      const float rinv = __builtin_amdgcn_rcpf(lr);
      const int q = qw + qh * 16 + l15;
      #pragma unroll
      for (int mf = 0; mf < 4; mf++) {
        const f32x4 o = oacc[mf][qh];
        const uint2 u = make_uint2(cvtpk(o[0] * rinv, o[1] * rinv),
                                   cvtpk(o[2] * rinv, o[3] * rinv));
        *(uint2*)(attnout + ((size_t)b * S_ + q) * (H_ * HD_) + h * 64 + mf * 16 + lq * 4) = u;
      }
    }
  }
}

extern "C" void kernel_launch(void* const* d_in, const int* in_sizes, int n_in,
                              void* d_out, int out_size, void* d_ws, size_t ws_size,
                              hipStream_t stream) {
  const float* query = (const float*)d_in[0];
  const float* key_  = (const float*)d_in[1];
  const float* value = (const float*)d_in[2];
  // d_in[3] = causal mask — implied analytically
  const float* Wq = (const float*)d_in[4];
  const float* Wk = (const float*)d_in[5];
  const float* Wv = (const float*)d_in[6];
  const float* Wo = (const float*)d_in[7];
  const float* bo = (const float*)d_in[8];
  float* out = (float*)d_out;

  char* ws = (char*)d_ws;
  const size_t MB = (size_t)1 << 20;
  short* Xbuf = (short*)(ws);             // 16 MB: attn output
  short* Wqt  = (short*)(ws + 16 * MB);
  short* Wkt  = (short*)(ws + 18 * MB);
  short* Wvt  = (short*)(ws + 20 * MB);
  short* Wot  = (short*)(ws + 22 * MB);
  short* Qh   = (short*)(ws + 24 * MB);   // 16 MB [B][H][S][HD], pre-scaled by 0.125*log2e
  short* Kh   = (short*)(ws + 40 * MB);   // 16 MB [B][H][S][HD]
  short* Vt   = (short*)(ws + 56 * MB);   // 16 MB [B][H][HD][S]   (total 72 MB)

  const dim3 tb(32, 8);
  const dim3 tg4(32, 32, 4);
  const float QSCALE = 0.125f * 1.4426950408889634f;  // fold 1/sqrt(HD) * log2(e) into Q

  transpose_cast_w4<<<tg4, tb, 0, stream>>>(Wq, Wk, Wv, Wo, Wqt, Wkt, Wvt, Wot);

  gemm8<<<dim3(4, 32, 3), 512, 0, stream>>>(query, key_, value, Wqt, Wkt, Wvt,
                                            Qh, Kh, Vt, QSCALE);

  attn_kernel<<<dim3(512), 256, 0, stream>>>(Qh, Kh, Vt, Xbuf);

  gemm_o<<<dim3(8, 64), 256, 0, stream>>>(Xbuf, Wot, out, bo);
}

// Round 18
// 198.493 us; speedup vs baseline: 1.1352x; 1.1352x over previous
//
#include <hip/hip_runtime.h>

#define B_ 4
#define S_ 2048
#define D_ 1024
#define H_ 16
#define HD_ 64

typedef __attribute__((ext_vector_type(8))) short bf16x8;
typedef __attribute__((ext_vector_type(4))) float f32x4;
typedef __attribute__((ext_vector_type(4))) unsigned u32x4;

__device__ __forceinline__ short f2bf(float f) {
  unsigned u = __builtin_bit_cast(unsigned, f);
  u += 0x7fffu + ((u >> 16) & 1u);   // RNE
  return (short)(u >> 16);
}

// HW packed f32x2 -> bf16x2 (RNE); no builtin on gfx950 -> inline asm (T12)
__device__ __forceinline__ unsigned cvtpk(float a, float b) {
  unsigned r;
  asm("v_cvt_pk_bf16_f32 %0, %1, %2" : "=v"(r) : "v"(a), "v"(b));
  return r;
}

__device__ __forceinline__ void gload_lds16(const void* g, void* l) {
  __builtin_amdgcn_global_load_lds((const __attribute__((address_space(1))) void*)g,
                                   (__attribute__((address_space(3))) void*)l, 16, 0, 0);
}

// swizzled LDS bf16x8 read from a [rows][64] bf16 tile (128B rows, T2 XOR swizzle)
__device__ __forceinline__ bf16x8 ldsw8(const short* base, int row, int colb) {
  const int off = (row * 128 + colb) ^ ((row & 7) << 4);
  return *(const bf16x8*)((const char*)base + off);
}

// pair-row swizzle for 64B-row bf16 tiles ([rows][32 shorts]): logical (row, cbyte)
// -> byte offset. Per-16-lane slot = ((row&1)*4+lq) ^ ((row>>1)&7): all 8 slots x2 = free.
__device__ __forceinline__ int bpr_off(int row, int cbyte) {
  return ((row >> 1) << 7) + ((((row & 1) << 6) + cbyte) ^ (((row >> 1) & 7) << 4));
}

#define MFMA16(a, b, c) __builtin_amdgcn_mfma_f32_16x16x32_bf16((a), (b), (c), 0, 0, 0)

// ---------------- 4x W [K][N] f32 -> Wt [N][K] bf16, one dispatch ----------------
__global__ void transpose_cast_w4(const float* __restrict__ W0, const float* __restrict__ W1,
                                  const float* __restrict__ W2, const float* __restrict__ W3,
                                  short* __restrict__ T0, short* __restrict__ T1,
                                  short* __restrict__ T2, short* __restrict__ T3) {
  __shared__ float tile[32][33];
  const int z = blockIdx.z;
  const float* W = z == 0 ? W0 : z == 1 ? W1 : z == 2 ? W2 : W3;
  short* Wt = z == 0 ? T0 : z == 1 ? T1 : z == 2 ? T2 : T3;
  const int n0 = blockIdx.x * 32, k0 = blockIdx.y * 32;
  const int tx = threadIdx.x, ty = threadIdx.y;  // 32 x 8
  #pragma unroll
  for (int i = ty; i < 32; i += 8)
    tile[i][tx] = W[(size_t)(k0 + i) * 1024 + n0 + tx];
  __syncthreads();
  #pragma unroll
  for (int i = ty; i < 32; i += 8)
    Wt[(size_t)(n0 + i) * 1024 + k0 + tx] = f2bf(tile[tx][i]);
}

// ---------------- fused QKV GEMM (R6/R12 proven): C = cast_bf16(A_f32) @ Wt^T ----------------
// A staged as raw f32 (XOR-swizzled source); B pair-row swizzled; 2-barrier loop.
// z==0: Q out [B][H][S][HD]*qscale; z==1: K out; z==2: V out [B][H][HD][S].
__global__ __launch_bounds__(256) void gemm_qkv(const float* __restrict__ Aq,
                                                const float* __restrict__ Ak,
                                                const float* __restrict__ Av,
                                                const short* __restrict__ Bq,
                                                const short* __restrict__ Bk,
                                                const short* __restrict__ Bv,
                                                short* __restrict__ Oq,
                                                short* __restrict__ Ok,
                                                short* __restrict__ Ov,
                                                float qscale) {
  __shared__ __align__(16) float Asf[2][128 * 32];   // 32 KB, f32 swizzled rows
  __shared__ __align__(16) short Bs[2][128 * 32];    // 16 KB, pair-row swizzled
  const int z = blockIdx.z;
  const float* A = z == 0 ? Aq : z == 1 ? Ak : Av;
  const short* Bt = z == 0 ? Bq : z == 1 ? Bk : Bv;
  short* outb = z == 0 ? Oq : z == 1 ? Ok : Ov;
  const float oscale = z == 0 ? qscale : 1.0f;

  const int tid = threadIdx.x;
  const int l = tid & 63, w = tid >> 6;
  const int wm = w >> 1, wn = w & 1;
  const int flat = blockIdx.x + (blockIdx.y << 3);
  const int xcd = flat & 7, t = flat >> 3;
  const int row0 = (xcd * 8 + (t & 7)) * 128;
  const int col0 = (t >> 3) * 128;
  const int l15 = l & 15, lq = l >> 4;

  f32x4 acc[4][4] = {};

  auto stageA = [&](int k0, int buf) {
    #pragma unroll
    for (int i = 0; i < 4; i++) {
      const int eoff = w * 4096 + i * 1024 + l * 16;   // byte offset in 16KB tile
      const int row = eoff >> 7;
      const int sc = (eoff & 127) ^ ((row & 7) << 4);  // inverse-swizzled src col
      gload_lds16((const char*)A + (size_t)(row0 + row) * 4096 + (size_t)k0 * 4 + sc,
                  (char*)Asf[buf] + w * 4096 + i * 1024);
    }
  };
  auto stageB = [&](int k0, int buf) {
    #pragma unroll
    for (int i = 0; i < 2; i++) {
      const int o = w * 2048 + i * 1024 + l * 16;      // dest byte in 8KB tile
      const int row2 = o >> 7;
      const int ip = (o & 127) ^ ((row2 & 7) << 4);
      const int row = row2 * 2 + (ip >> 6);
      const int cb = ip & 63;
      gload_lds16((const char*)Bt + ((size_t)(col0 + row) * 1024 + k0) * 2 + cb,
                  (char*)Bs[buf] + o);
    }
  };

  stageA(0, 0);
  stageB(0, 0);

  for (int kt = 0; kt < 32; ++kt) {
    __syncthreads();   // staging of buf kt&1 complete (vmcnt drained at barrier)
    if (kt + 1 < 32) {
      stageA((kt + 1) * 32, (kt + 1) & 1);
      stageB((kt + 1) * 32, (kt + 1) & 1);
    }
    const float* as = Asf[kt & 1];
    const short* bs = Bs[kt & 1];
    bf16x8 af[4], bfv[4];
    #pragma unroll
    for (int mf = 0; mf < 4; mf++) {
      const int R = wm * 64 + mf * 16 + l15;
      const int sw = (R & 7) << 4;
      const f32x4 g0 = *(const f32x4*)((const char*)as + R * 128 + ((lq * 32) ^ sw));
      const f32x4 g1 = *(const f32x4*)((const char*)as + R * 128 + ((lq * 32 + 16) ^ sw));
      const u32x4 uu = {cvtpk(g0[0], g0[1]), cvtpk(g0[2], g0[3]),
                        cvtpk(g1[0], g1[1]), cvtpk(g1[2], g1[3])};
      af[mf] = __builtin_bit_cast(bf16x8, uu);
    }
    #pragma unroll
    for (int nf = 0; nf < 4; nf++)
      bfv[nf] = *(const bf16x8*)((const char*)bs + bpr_off(wn * 64 + nf * 16 + l15, lq * 16));
    #pragma unroll
    for (int mf = 0; mf < 4; mf++)
      #pragma unroll
      for (int nf = 0; nf < 4; nf++)
        acc[mf][nf] = MFMA16(af[mf], bfv[nf], acc[mf][nf]);
  }

  // epilogue: C/D layout col=lane&15, row=(lane>>4)*4+reg
  #pragma unroll
  for (int mf = 0; mf < 4; mf++) {
    #pragma unroll
    for (int nf = 0; nf < 4; nf++) {
      #pragma unroll
      for (int r = 0; r < 4; r++) {
        const int gr = row0 + wm * 64 + mf * 16 + lq * 4 + r;  // m = b*S + s
        const int gc = col0 + wn * 64 + nf * 16 + l15;         // n = h*64 + hd
        const int b = gr >> 11, s = gr & 2047;
        const int h = gc >> 6, hd = gc & 63;
        const float v = acc[mf][nf][r];
        if (z < 2)
          outb[(((size_t)(b * H_ + h)) * S_ + s) * HD_ + hd] = f2bf(v * oscale);
        else
          outb[(((size_t)(b * H_ + h)) * HD_ + hd) * S_ + s] = f2bf(v);
      }
    }
  }
}

// ---------------- O-projection GEMM (R6 proven): f32 out = A_bf16 @ Wot^T + bias ----------------
__global__ __launch_bounds__(256) void gemm_o(const short* __restrict__ A,
                                              const short* __restrict__ Bt,
                                              float* __restrict__ outf,
                                              const float* __restrict__ bias) {
  __shared__ __align__(16) short As[2][128 * 32];
  __shared__ __align__(16) short Bs[2][128 * 32];
  const int tid = threadIdx.x;
  const int l = tid & 63;
  const int w = tid >> 6;
  const int wm = w >> 1, wn = w & 1;
  const int flat = blockIdx.x + (blockIdx.y << 3);
  const int xcd = flat & 7, t = flat >> 3;
  const int row0 = (xcd * 8 + (t & 7)) * 128;
  const int col0 = (t >> 3) * 128;
  const int l15 = l & 15, lq = l >> 4;

  f32x4 acc[4][4] = {};

  auto stage = [&](const short* src, int r0, int k0, short* lds) {
    #pragma unroll
    for (int i = 0; i < 2; i++) {
      const int o = w * 2048 + i * 1024 + l * 16;      // dest byte in 8KB tile
      const int row2 = o >> 7;
      const int ip = (o & 127) ^ ((row2 & 7) << 4);
      const int row = row2 * 2 + (ip >> 6);
      const int cb = ip & 63;
      gload_lds16((const char*)src + ((size_t)(r0 + row) * 1024 + k0) * 2 + cb,
                  (char*)lds + o);
    }
  };

  stage(A, row0, 0, As[0]);
  stage(Bt, col0, 0, Bs[0]);

  for (int kt = 0; kt < 32; ++kt) {
    __syncthreads();
    if (kt + 1 < 32) {
      stage(A, row0, (kt + 1) * 32, As[(kt + 1) & 1]);
      stage(Bt, col0, (kt + 1) * 32, Bs[(kt + 1) & 1]);
    }
    const short* as = As[kt & 1];
    const short* bs = Bs[kt & 1];
    bf16x8 af[4], bfv[4];
    #pragma unroll
    for (int mf = 0; mf < 4; mf++)
      af[mf] = *(const bf16x8*)((const char*)as + bpr_off(wm * 64 + mf * 16 + l15, lq * 16));
    #pragma unroll
    for (int nf = 0; nf < 4; nf++)
      bfv[nf] = *(const bf16x8*)((const char*)bs + bpr_off(wn * 64 + nf * 16 + l15, lq * 16));
    #pragma unroll
    for (int mf = 0; mf < 4; mf++)
      #pragma unroll
      for (int nf = 0; nf < 4; nf++)
        acc[mf][nf] = MFMA16(af[mf], bfv[nf], acc[mf][nf]);
  }

  #pragma unroll
  for (int mf = 0; mf < 4; mf++)
    #pragma unroll
    for (int nf = 0; nf < 4; nf++)
      #pragma unroll
      for (int r = 0; r < 4; r++) {
        const int gr = row0 + wm * 64 + mf * 16 + lq * 4 + r;
        const int gc = col0 + wn * 64 + nf * 16 + l15;
        outf[(size_t)gr * 1024 + gc] = acc[mf][nf][r] + bias[gc];
      }
}

// ---------------- causal flash attention (R12 EXACT, known-pass) ----------------
__global__ __launch_bounds__(256) void attn_kernel(const short* __restrict__ Qh,
                                                   const short* __restrict__ Kh,
                                                   const short* __restrict__ Vtr,
                                                   short* __restrict__ attnout) {
  __shared__ __align__(16) short Ks[2][64 * 64];   // [kv][hd] swizzled
  __shared__ __align__(16) short Vs[2][64 * 64];   // [hd][kv] swizzled
  __shared__ __align__(16) short Ps[4][32 * 64];   // per-wave P[q][kv] swizzled
  const int tid = threadIdx.x, l = tid & 63, w = tid >> 6;
  const int l15 = l & 15, lq = l >> 4;
  const int flat = blockIdx.x;
  const int vid = (flat & 7) * 64 + (flat >> 3);   // 8 bh per XCD (K+V working set ~4MB = L2)
  const int bh = vid >> 3, pairx = vid & 7;
  const int b = bh >> 4, h = bh & 15;
  const size_t base = (size_t)bh * (S_ * HD_);
  const short* Qp = Qh + base;
  const short* Kp = Kh + base;
  const short* Vp = Vtr + base;   // [64][2048]
  short* Pw = (short*)Ps[w];

  for (int pass = 0; pass < 2; ++pass) {
    const int qt = pass ? 15 - pairx : pairx;      // diagonal pairing: total work uniform
    const int q0 = qt * 128;
    const int qw = q0 + w * 32;
    const int nkt = (q0 >> 6) + 2;

    // Q B-fragments (q already pre-scaled by 0.125*log2e in the Q projection)
    bf16x8 qf[2][2];
    #pragma unroll
    for (int qh = 0; qh < 2; qh++)
      #pragma unroll
      for (int ks = 0; ks < 2; ks++)
        qf[qh][ks] = *(const bf16x8*)(Qp + (size_t)(qw + qh * 16 + l15) * 64 + ks * 32 + lq * 8);

    f32x4 oacc[4][2] = {};          // [hd-frag][q-half]: O^T, rows hd, cols q=l15
    float mrow[2] = {-1e30f, -1e30f};
    float lpart[2] = {0.f, 0.f};    // per-lane partial row-sum (reduced only at epilogue)

    auto stage = [&](int kt, int bf) {
      const int k0s = kt << 6;
      #pragma unroll
      for (int i = 0; i < 2; i++) {
        const int o = w * 2048 + i * 1024 + l * 16;          // byte offset in 8KB tile
        const int sw = o ^ (((o >> 7) & 7) << 4);            // inverse-swizzled source (rule 21)
        gload_lds16((const char*)Kp + (size_t)k0s * 128 + sw, (char*)Ks[bf] + o);
        gload_lds16(Vp + (size_t)(o >> 7) * S_ + k0s + ((sw & 127) >> 1), (char*)Vs[bf] + o);
      }
    };

    stage(0, 0);
    __syncthreads();

    for (int kt = 0; kt < nkt; ++kt) {
      const int cur = kt & 1;
      if (kt + 1 < nkt) stage(kt + 1, cur ^ 1);   // prefetch in flight across compute
      const int k0 = kt << 6;

      if (k0 <= qw + 31) {                         // wave-level fully-masked-tile skip
        // --- QK^T swapped: sacc[qh][mf] holds S^T[kv=16mf+4lq+r][q=16qh+l15] ---
        f32x4 sacc[2][4] = {};
        __builtin_amdgcn_s_setprio(1);
        #pragma unroll
        for (int ks = 0; ks < 2; ks++) {
          #pragma unroll
          for (int mf = 0; mf < 4; mf++) {
            const bf16x8 kf = ldsw8(Ks[cur], mf * 16 + l15, ks * 64 + lq * 16);
            #pragma unroll
            for (int qh = 0; qh < 2; qh++)
              sacc[qh][mf] = MFMA16(kf, qf[qh][ks], sacc[qh][mf]);
          }
        }
        __builtin_amdgcn_s_setprio(0);

        // causal mask — only diagonal tiles
        if (k0 + 63 > qw) {
          #pragma unroll
          for (int qh = 0; qh < 2; qh++) {
            const int qg = qw + qh * 16 + l15 - lq * 4;   // kv>q  <=>  k0+16mf+r > qg
            #pragma unroll
            for (int mf = 0; mf < 4; mf++)
              #pragma unroll
              for (int r = 0; r < 4; r++)
                if (k0 + mf * 16 + r > qg) sacc[qh][mf][r] = -1e30f;
          }
        }

        // per-lane local max: balanced tree (v_max3-fusible), no shfl unless rescale fires
        float mxl[2];
        #pragma unroll
        for (int qh = 0; qh < 2; qh++) {
          float t0 = fmaxf(fmaxf(sacc[qh][0][0], sacc[qh][0][1]),
                           fmaxf(sacc[qh][0][2], sacc[qh][0][3]));
          float t1 = fmaxf(fmaxf(sacc[qh][1][0], sacc[qh][1][1]),
                           fmaxf(sacc[qh][1][2], sacc[qh][1][3]));
          float t2 = fmaxf(fmaxf(sacc[qh][2][0], sacc[qh][2][1]),
                           fmaxf(sacc[qh][2][2], sacc[qh][2][3]));
          float t3 = fmaxf(fmaxf(sacc[qh][3][0], sacc[qh][3][1]),
                           fmaxf(sacc[qh][3][2], sacc[qh][3][3]));
          mxl[qh] = fmaxf(fmaxf(t0, t1), fmaxf(t2, t3));
        }

        // defer-max (T13, THR=8 in log2 domain); lane-max trigger == row-max trigger
        const bool need = (mxl[0] > mrow[0] + 8.f) || (mxl[1] > mrow[1] + 8.f);
        if (__any(need)) {
          #pragma unroll
          for (int qh = 0; qh < 2; qh++) {
            float m = fmaxf(mxl[qh], __shfl_xor(mxl[qh], 16));
            m = fmaxf(m, __shfl_xor(m, 32));
            const float mn = fmaxf(mrow[qh], m);
            const float fac = __builtin_amdgcn_exp2f(mrow[qh] - mn);
            mrow[qh] = mn;
            lpart[qh] *= fac;
            #pragma unroll
            for (int mf = 0; mf < 4; mf++) oacc[mf][qh] *= fac;
          }
        }

        // exp2, per-lane sum, HW-packed P -> per-wave LDS (8 x ds_write_b64)
        #pragma unroll
        for (int qh = 0; qh < 2; qh++) {
          float rs = 0.f;
          const int row = qh * 16 + l15;
          #pragma unroll
          for (int mf = 0; mf < 4; mf++) {
            f32x4 p;
            #pragma unroll
            for (int r = 0; r < 4; r++) {
              const float e = __builtin_amdgcn_exp2f(sacc[qh][mf][r] - mrow[qh]);
              p[r] = e;
              rs += e;
            }
            const int off = (row * 128 + mf * 32 + lq * 8) ^ ((row & 7) << 4);
            *(uint2*)((char*)Pw + off) = make_uint2(cvtpk(p[0], p[1]), cvtpk(p[2], p[3]));
          }
          lpart[qh] += rs;
        }

        asm volatile("s_waitcnt lgkmcnt(0)" ::: "memory");
        __builtin_amdgcn_sched_barrier(0);

        // --- PV swapped: oacc[mf][qh] += V^T-frag x P^T-frag ---
        __builtin_amdgcn_s_setprio(1);
        #pragma unroll
        for (int ks = 0; ks < 2; ks++) {
          bf16x8 pb[2];
          #pragma unroll
          for (int qh = 0; qh < 2; qh++) {
            const int row = qh * 16 + l15;
            const int off = (row * 128 + ks * 64 + lq * 16) ^ ((row & 7) << 4);
            pb[qh] = *(const bf16x8*)((const char*)Pw + off);
          }
          #pragma unroll
          for (int mf = 0; mf < 4; mf++) {
            const bf16x8 vf = ldsw8(Vs[cur], mf * 16 + l15, ks * 64 + lq * 16);
            #pragma unroll
            for (int qh = 0; qh < 2; qh++)
              oacc[mf][qh] = MFMA16(vf, pb[qh], oacc[mf][qh]);
          }
        }
        __builtin_amdgcn_s_setprio(0);
      }
      __syncthreads();   // prefetch drained (vmcnt) + all waves done with buf cur
    }

    // epilogue: O^T rows hd=16mf+4lq+r, col q=16qh+l15 -> attnout [B][S][H*HD]
    #pragma unroll
    for (int qh = 0; qh < 2; qh++) {
      float lr = lpart[qh];
      lr += __shfl_xor(lr, 16);
      lr += __shfl_xor(lr, 32);
      const float rinv = __builtin_amdgcn_rcpf(lr);
      const int q = qw + qh * 16 + l15;
      #pragma unroll
      for (int mf = 0; mf < 4; mf++) {
        const f32x4 o = oacc[mf][qh];
        const uint2 u = make_uint2(cvtpk(o[0] * rinv, o[1] * rinv),
                                   cvtpk(o[2] * rinv, o[3] * rinv));
        *(uint2*)(attnout + ((size_t)b * S_ + q) * (H_ * HD_) + h * 64 + mf * 16 + lq * 4) = u;
      }
    }
  }
}

extern "C" void kernel_launch(void* const* d_in, const int* in_sizes, int n_in,
                              void* d_out, int out_size, void* d_ws, size_t ws_size,
                              hipStream_t stream) {
  const float* query = (const float*)d_in[0];
  const float* key_  = (const float*)d_in[1];
  const float* value = (const float*)d_in[2];
  // d_in[3] = causal mask — implied analytically
  const float* Wq = (const float*)d_in[4];
  const float* Wk = (const float*)d_in[5];
  const float* Wv = (const float*)d_in[6];
  const float* Wo = (const float*)d_in[7];
  const float* bo = (const float*)d_in[8];
  float* out = (float*)d_out;

  char* ws = (char*)d_ws;
  const size_t MB = (size_t)1 << 20;
  short* Xbuf = (short*)(ws);             // 16 MB: attn output
  short* Wqt  = (short*)(ws + 16 * MB);
  short* Wkt  = (short*)(ws + 18 * MB);
  short* Wvt  = (short*)(ws + 20 * MB);
  short* Wot  = (short*)(ws + 22 * MB);
  short* Qh   = (short*)(ws + 24 * MB);   // 16 MB [B][H][S][HD], pre-scaled by 0.125*log2e
  short* Kh   = (short*)(ws + 40 * MB);   // 16 MB [B][H][S][HD]
  short* Vt   = (short*)(ws + 56 * MB);   // 16 MB [B][H][HD][S]   (total 72 MB)

  const dim3 tb(32, 8);
  const dim3 tg4(32, 32, 4);
  const float QSCALE = 0.125f * 1.4426950408889634f;  // fold 1/sqrt(HD) * log2(e) into Q

  transpose_cast_w4<<<tg4, tb, 0, stream>>>(Wq, Wk, Wv, Wo, Wqt, Wkt, Wvt, Wot);

  gemm_qkv<<<dim3(8, 64, 3), 256, 0, stream>>>(query, key_, value, Wqt, Wkt, Wvt,
                                               Qh, Kh, Vt, QSCALE);

  attn_kernel<<<dim3(512), 256, 0, stream>>>(Qh, Kh, Vt, Xbuf);

  gemm_o<<<dim3(8, 64), 256, 0, stream>>>(Xbuf, Wot, out, bo);
}

// Round 20
// 198.487 us; speedup vs baseline: 1.1352x; 1.0000x over previous
//
#include <hip/hip_runtime.h>

#define B_ 4
#define S_ 2048
#define D_ 1024
#define H_ 16
#define HD_ 64

typedef __attribute__((ext_vector_type(8))) short bf16x8;
typedef __attribute__((ext_vector_type(4))) float f32x4;
typedef __attribute__((ext_vector_type(4))) unsigned u32x4;

__device__ __forceinline__ short f2bf(float f) {
  unsigned u = __builtin_bit_cast(unsigned, f);
  u += 0x7fffu + ((u >> 16) & 1u);   // RNE
  return (short)(u >> 16);
}

// HW packed f32x2 -> bf16x2 (RNE); no builtin on gfx950 -> inline asm (T12)
__device__ __forceinline__ unsigned cvtpk(float a, float b) {
  unsigned r;
  asm("v_cvt_pk_bf16_f32 %0, %1, %2" : "=v"(r) : "v"(a), "v"(b));
  return r;
}

__device__ __forceinline__ void gload_lds16(const void* g, void* l) {
  __builtin_amdgcn_global_load_lds((const __attribute__((address_space(1))) void*)g,
                                   (__attribute__((address_space(3))) void*)l, 16, 0, 0);
}

// swizzled LDS bf16x8 read from a [rows][64] bf16 tile (128B rows, T2 XOR swizzle)
__device__ __forceinline__ bf16x8 ldsw8(const short* base, int row, int colb) {
  const int off = (row * 128 + colb) ^ ((row & 7) << 4);
  return *(const bf16x8*)((const char*)base + off);
}

// pair-row swizzle for 64B-row bf16 tiles ([rows][32 shorts]): logical (row, cbyte)
// -> byte offset. Per-16-lane slot = ((row&1)*4+lq) ^ ((row>>1)&7): all 8 slots x2 = free.
__device__ __forceinline__ int bpr_off(int row, int cbyte) {
  return ((row >> 1) << 7) + ((((row & 1) << 6) + cbyte) ^ (((row >> 1) & 7) << 4));
}

#define MFMA16(a, b, c) __builtin_amdgcn_mfma_f32_16x16x32_bf16((a), (b), (c), 0, 0, 0)

// ---------------- 4x W [K][N] f32 -> Wt [N][K] bf16, one dispatch ----------------
__global__ void transpose_cast_w4(const float* __restrict__ W0, const float* __restrict__ W1,
                                  const float* __restrict__ W2, const float* __restrict__ W3,
                                  short* __restrict__ T0, short* __restrict__ T1,
                                  short* __restrict__ T2, short* __restrict__ T3) {
  __shared__ float tile[32][33];
  const int z = blockIdx.z;
  const float* W = z == 0 ? W0 : z == 1 ? W1 : z == 2 ? W2 : W3;
  short* Wt = z == 0 ? T0 : z == 1 ? T1 : z == 2 ? T2 : T3;
  const int n0 = blockIdx.x * 32, k0 = blockIdx.y * 32;
  const int tx = threadIdx.x, ty = threadIdx.y;  // 32 x 8
  #pragma unroll
  for (int i = ty; i < 32; i += 8)
    tile[i][tx] = W[(size_t)(k0 + i) * 1024 + n0 + tx];
  __syncthreads();
  #pragma unroll
  for (int i = ty; i < 32; i += 8)
    Wt[(size_t)(n0 + i) * 1024 + k0 + tx] = f2bf(tile[tx][i]);
}

// ---------------- fused QKV GEMM (R6/R12 proven): C = cast_bf16(A_f32) @ Wt^T ----------------
// A staged as raw f32 (XOR-swizzled source); B pair-row swizzled; 2-barrier loop.
// z==0: Q out [B][H][S][HD]*qscale; z==1: K out; z==2: V out [B][H][HD][S].
__global__ __launch_bounds__(256) void gemm_qkv(const float* __restrict__ Aq,
                                                const float* __restrict__ Ak,
                                                const float* __restrict__ Av,
                                                const short* __restrict__ Bq,
                                                const short* __restrict__ Bk,
                                                const short* __restrict__ Bv,
                                                short* __restrict__ Oq,
                                                short* __restrict__ Ok,
                                                short* __restrict__ Ov,
                                                float qscale) {
  __shared__ __align__(16) float Asf[2][128 * 32];   // 32 KB, f32 swizzled rows
  __shared__ __align__(16) short Bs[2][128 * 32];    // 16 KB, pair-row swizzled
  const int z = blockIdx.z;
  const float* A = z == 0 ? Aq : z == 1 ? Ak : Av;
  const short* Bt = z == 0 ? Bq : z == 1 ? Bk : Bv;
  short* outb = z == 0 ? Oq : z == 1 ? Ok : Ov;
  const float oscale = z == 0 ? qscale : 1.0f;

  const int tid = threadIdx.x;
  const int l = tid & 63, w = tid >> 6;
  const int wm = w >> 1, wn = w & 1;
  const int flat = blockIdx.x + (blockIdx.y << 3);
  const int xcd = flat & 7, t = flat >> 3;
  const int row0 = (xcd * 8 + (t & 7)) * 128;
  const int col0 = (t >> 3) * 128;
  const int l15 = l & 15, lq = l >> 4;

  f32x4 acc[4][4] = {};

  auto stageA = [&](int k0, int buf) {
    #pragma unroll
    for (int i = 0; i < 4; i++) {
      const int eoff = w * 4096 + i * 1024 + l * 16;   // byte offset in 16KB tile
      const int row = eoff >> 7;
      const int sc = (eoff & 127) ^ ((row & 7) << 4);  // inverse-swizzled src col
      gload_lds16((const char*)A + (size_t)(row0 + row) * 4096 + (size_t)k0 * 4 + sc,
                  (char*)Asf[buf] + w * 4096 + i * 1024);
    }
  };
  auto stageB = [&](int k0, int buf) {
    #pragma unroll
    for (int i = 0; i < 2; i++) {
      const int o = w * 2048 + i * 1024 + l * 16;      // dest byte in 8KB tile
      const int row2 = o >> 7;
      const int ip = (o & 127) ^ ((row2 & 7) << 4);
      const int row = row2 * 2 + (ip >> 6);
      const int cb = ip & 63;
      gload_lds16((const char*)Bt + ((size_t)(col0 + row) * 1024 + k0) * 2 + cb,
                  (char*)Bs[buf] + o);
    }
  };

  stageA(0, 0);
  stageB(0, 0);

  for (int kt = 0; kt < 32; ++kt) {
    __syncthreads();   // staging of buf kt&1 complete (vmcnt drained at barrier)
    if (kt + 1 < 32) {
      stageA((kt + 1) * 32, (kt + 1) & 1);
      stageB((kt + 1) * 32, (kt + 1) & 1);
    }
    const float* as = Asf[kt & 1];
    const short* bs = Bs[kt & 1];
    bf16x8 af[4], bfv[4];
    #pragma unroll
    for (int mf = 0; mf < 4; mf++) {
      const int R = wm * 64 + mf * 16 + l15;
      const int sw = (R & 7) << 4;
      const f32x4 g0 = *(const f32x4*)((const char*)as + R * 128 + ((lq * 32) ^ sw));
      const f32x4 g1 = *(const f32x4*)((const char*)as + R * 128 + ((lq * 32 + 16) ^ sw));
      const u32x4 uu = {cvtpk(g0[0], g0[1]), cvtpk(g0[2], g0[3]),
                        cvtpk(g1[0], g1[1]), cvtpk(g1[2], g1[3])};
      af[mf] = __builtin_bit_cast(bf16x8, uu);
    }
    #pragma unroll
    for (int nf = 0; nf < 4; nf++)
      bfv[nf] = *(const bf16x8*)((const char*)bs + bpr_off(wn * 64 + nf * 16 + l15, lq * 16));
    #pragma unroll
    for (int mf = 0; mf < 4; mf++)
      #pragma unroll
      for (int nf = 0; nf < 4; nf++)
        acc[mf][nf] = MFMA16(af[mf], bfv[nf], acc[mf][nf]);
  }

  // epilogue: C/D layout col=lane&15, row=(lane>>4)*4+reg
  #pragma unroll
  for (int mf = 0; mf < 4; mf++) {
    #pragma unroll
    for (int nf = 0; nf < 4; nf++) {
      #pragma unroll
      for (int r = 0; r < 4; r++) {
        const int gr = row0 + wm * 64 + mf * 16 + lq * 4 + r;  // m = b*S + s
        const int gc = col0 + wn * 64 + nf * 16 + l15;         // n = h*64 + hd
        const int b = gr >> 11, s = gr & 2047;
        const int h = gc >> 6, hd = gc & 63;
        const float v = acc[mf][nf][r];
        if (z < 2)
          outb[(((size_t)(b * H_ + h)) * S_ + s) * HD_ + hd] = f2bf(v * oscale);
        else
          outb[(((size_t)(b * H_ + h)) * HD_ + hd) * S_ + s] = f2bf(v);
      }
    }
  }
}

// ---------------- O-projection GEMM (R6 proven): f32 out = A_bf16 @ Wot^T + bias ----------------
__global__ __launch_bounds__(256) void gemm_o(const short* __restrict__ A,
                                              const short* __restrict__ Bt,
                                              float* __restrict__ outf,
                                              const float* __restrict__ bias) {
  __shared__ __align__(16) short As[2][128 * 32];
  __shared__ __align__(16) short Bs[2][128 * 32];
  const int tid = threadIdx.x;
  const int l = tid & 63;
  const int w = tid >> 6;
  const int wm = w >> 1, wn = w & 1;
  const int flat = blockIdx.x + (blockIdx.y << 3);
  const int xcd = flat & 7, t = flat >> 3;
  const int row0 = (xcd * 8 + (t & 7)) * 128;
  const int col0 = (t >> 3) * 128;
  const int l15 = l & 15, lq = l >> 4;

  f32x4 acc[4][4] = {};

  auto stage = [&](const short* src, int r0, int k0, short* lds) {
    #pragma unroll
    for (int i = 0; i < 2; i++) {
      const int o = w * 2048 + i * 1024 + l * 16;      // dest byte in 8KB tile
      const int row2 = o >> 7;
      const int ip = (o & 127) ^ ((row2 & 7) << 4);
      const int row = row2 * 2 + (ip >> 6);
      const int cb = ip & 63;
      gload_lds16((const char*)src + ((size_t)(r0 + row) * 1024 + k0) * 2 + cb,
                  (char*)lds + o);
    }
  };

  stage(A, row0, 0, As[0]);
  stage(Bt, col0, 0, Bs[0]);

  for (int kt = 0; kt < 32; ++kt) {
    __syncthreads();
    if (kt + 1 < 32) {
      stage(A, row0, (kt + 1) * 32, As[(kt + 1) & 1]);
      stage(Bt, col0, (kt + 1) * 32, Bs[(kt + 1) & 1]);
    }
    const short* as = As[kt & 1];
    const short* bs = Bs[kt & 1];
    bf16x8 af[4], bfv[4];
    #pragma unroll
    for (int mf = 0; mf < 4; mf++)
      af[mf] = *(const bf16x8*)((const char*)as + bpr_off(wm * 64 + mf * 16 + l15, lq * 16));
    #pragma unroll
    for (int nf = 0; nf < 4; nf++)
      bfv[nf] = *(const bf16x8*)((const char*)bs + bpr_off(wn * 64 + nf * 16 + l15, lq * 16));
    #pragma unroll
    for (int mf = 0; mf < 4; mf++)
      #pragma unroll
      for (int nf = 0; nf < 4; nf++)
        acc[mf][nf] = MFMA16(af[mf], bfv[nf], acc[mf][nf]);
  }

  #pragma unroll
  for (int mf = 0; mf < 4; mf++)
    #pragma unroll
    for (int nf = 0; nf < 4; nf++)
      #pragma unroll
      for (int r = 0; r < 4; r++) {
        const int gr = row0 + wm * 64 + mf * 16 + lq * 4 + r;
        const int gc = col0 + wn * 64 + nf * 16 + l15;
        outf[(size_t)gr * 1024 + gc] = acc[mf][nf][r] + bias[gc];
      }
}

// ---------------- causal flash attention (R12 EXACT, known-pass) ----------------
__global__ __launch_bounds__(256) void attn_kernel(const short* __restrict__ Qh,
                                                   const short* __restrict__ Kh,
                                                   const short* __restrict__ Vtr,
                                                   short* __restrict__ attnout) {
  __shared__ __align__(16) short Ks[2][64 * 64];   // [kv][hd] swizzled
  __shared__ __align__(16) short Vs[2][64 * 64];   // [hd][kv] swizzled
  __shared__ __align__(16) short Ps[4][32 * 64];   // per-wave P[q][kv] swizzled
  const int tid = threadIdx.x, l = tid & 63, w = tid >> 6;
  const int l15 = l & 15, lq = l >> 4;
  const int flat = blockIdx.x;
  const int vid = (flat & 7) * 64 + (flat >> 3);   // 8 bh per XCD (K+V working set ~4MB = L2)
  const int bh = vid >> 3, pairx = vid & 7;
  const int b = bh >> 4, h = bh & 15;
  const size_t base = (size_t)bh * (S_ * HD_);
  const short* Qp = Qh + base;
  const short* Kp = Kh + base;
  const short* Vp = Vtr + base;   // [64][2048]
  short* Pw = (short*)Ps[w];

  for (int pass = 0; pass < 2; ++pass) {
    const int qt = pass ? 15 - pairx : pairx;      // diagonal pairing: total work uniform
    const int q0 = qt * 128;
    const int qw = q0 + w * 32;
    const int nkt = (q0 >> 6) + 2;

    // Q B-fragments (q already pre-scaled by 0.125*log2e in the Q projection)
    bf16x8 qf[2][2];
    #pragma unroll
    for (int qh = 0; qh < 2; qh++)
      #pragma unroll
      for (int ks = 0; ks < 2; ks++)
        qf[qh][ks] = *(const bf16x8*)(Qp + (size_t)(qw + qh * 16 + l15) * 64 + ks * 32 + lq * 8);

    f32x4 oacc[4][2] = {};          // [hd-frag][q-half]: O^T, rows hd, cols q=l15
    float mrow[2] = {-1e30f, -1e30f};
    float lpart[2] = {0.f, 0.f};    // per-lane partial row-sum (reduced only at epilogue)

    auto stage = [&](int kt, int bf) {
      const int k0s = kt << 6;
      #pragma unroll
      for (int i = 0; i < 2; i++) {
        const int o = w * 2048 + i * 1024 + l * 16;          // byte offset in 8KB tile
        const int sw = o ^ (((o >> 7) & 7) << 4);            // inverse-swizzled source (rule 21)
        gload_lds16((const char*)Kp + (size_t)k0s * 128 + sw, (char*)Ks[bf] + o);
        gload_lds16(Vp + (size_t)(o >> 7) * S_ + k0s + ((sw & 127) >> 1), (char*)Vs[bf] + o);
      }
    };

    stage(0, 0);
    __syncthreads();

    for (int kt = 0; kt < nkt; ++kt) {
      const int cur = kt & 1;
      if (kt + 1 < nkt) stage(kt + 1, cur ^ 1);   // prefetch in flight across compute
      const int k0 = kt << 6;

      if (k0 <= qw + 31) {                         // wave-level fully-masked-tile skip
        // --- QK^T swapped: sacc[qh][mf] holds S^T[kv=16mf+4lq+r][q=16qh+l15] ---
        f32x4 sacc[2][4] = {};
        __builtin_amdgcn_s_setprio(1);
        #pragma unroll
        for (int ks = 0; ks < 2; ks++) {
          #pragma unroll
          for (int mf = 0; mf < 4; mf++) {
            const bf16x8 kf = ldsw8(Ks[cur], mf * 16 + l15, ks * 64 + lq * 16);
            #pragma unroll
            for (int qh = 0; qh < 2; qh++)
              sacc[qh][mf] = MFMA16(kf, qf[qh][ks], sacc[qh][mf]);
          }
        }
        __builtin_amdgcn_s_setprio(0);

        // causal mask — only diagonal tiles
        if (k0 + 63 > qw) {
          #pragma unroll
          for (int qh = 0; qh < 2; qh++) {
            const int qg = qw + qh * 16 + l15 - lq * 4;   // kv>q  <=>  k0+16mf+r > qg
            #pragma unroll
            for (int mf = 0; mf < 4; mf++)
              #pragma unroll
              for (int r = 0; r < 4; r++)
                if (k0 + mf * 16 + r > qg) sacc[qh][mf][r] = -1e30f;
          }
        }

        // per-lane local max: balanced tree (v_max3-fusible), no shfl unless rescale fires
        float mxl[2];
        #pragma unroll
        for (int qh = 0; qh < 2; qh++) {
          float t0 = fmaxf(fmaxf(sacc[qh][0][0], sacc[qh][0][1]),
                           fmaxf(sacc[qh][0][2], sacc[qh][0][3]));
          float t1 = fmaxf(fmaxf(sacc[qh][1][0], sacc[qh][1][1]),
                           fmaxf(sacc[qh][1][2], sacc[qh][1][3]));
          float t2 = fmaxf(fmaxf(sacc[qh][2][0], sacc[qh][2][1]),
                           fmaxf(sacc[qh][2][2], sacc[qh][2][3]));
          float t3 = fmaxf(fmaxf(sacc[qh][3][0], sacc[qh][3][1]),
                           fmaxf(sacc[qh][3][2], sacc[qh][3][3]));
          mxl[qh] = fmaxf(fmaxf(t0, t1), fmaxf(t2, t3));
        }

        // defer-max (T13, THR=8 in log2 domain); lane-max trigger == row-max trigger
        const bool need = (mxl[0] > mrow[0] + 8.f) || (mxl[1] > mrow[1] + 8.f);
        if (__any(need)) {
          #pragma unroll
          for (int qh = 0; qh < 2; qh++) {
            float m = fmaxf(mxl[qh], __shfl_xor(mxl[qh], 16));
            m = fmaxf(m, __shfl_xor(m, 32));
            const float mn = fmaxf(mrow[qh], m);
            const float fac = __builtin_amdgcn_exp2f(mrow[qh] - mn);
            mrow[qh] = mn;
            lpart[qh] *= fac;
            #pragma unroll
            for (int mf = 0; mf < 4; mf++) oacc[mf][qh] *= fac;
          }
        }

        // exp2, per-lane sum, HW-packed P -> per-wave LDS (8 x ds_write_b64)
        #pragma unroll
        for (int qh = 0; qh < 2; qh++) {
          float rs = 0.f;
          const int row = qh * 16 + l15;
          #pragma unroll
          for (int mf = 0; mf < 4; mf++) {
            f32x4 p;
            #pragma unroll
            for (int r = 0; r < 4; r++) {
              const float e = __builtin_amdgcn_exp2f(sacc[qh][mf][r] - mrow[qh]);
              p[r] = e;
              rs += e;
            }
            const int off = (row * 128 + mf * 32 + lq * 8) ^ ((row & 7) << 4);
            *(uint2*)((char*)Pw + off) = make_uint2(cvtpk(p[0], p[1]), cvtpk(p[2], p[3]));
          }
          lpart[qh] += rs;
        }

        asm volatile("s_waitcnt lgkmcnt(0)" ::: "memory");
        __builtin_amdgcn_sched_barrier(0);

        // --- PV swapped: oacc[mf][qh] += V^T-frag x P^T-frag ---
        __builtin_amdgcn_s_setprio(1);
        #pragma unroll
        for (int ks = 0; ks < 2; ks++) {
          bf16x8 pb[2];
          #pragma unroll
          for (int qh = 0; qh < 2; qh++) {
            const int row = qh * 16 + l15;
            const int off = (row * 128 + ks * 64 + lq * 16) ^ ((row & 7) << 4);
            pb[qh] = *(const bf16x8*)((const char*)Pw + off);
          }
          #pragma unroll
          for (int mf = 0; mf < 4; mf++) {
            const bf16x8 vf = ldsw8(Vs[cur], mf * 16 + l15, ks * 64 + lq * 16);
            #pragma unroll
            for (int qh = 0; qh < 2; qh++)
              oacc[mf][qh] = MFMA16(vf, pb[qh], oacc[mf][qh]);
          }
        }
        __builtin_amdgcn_s_setprio(0);
      }
      __syncthreads();   // prefetch drained (vmcnt) + all waves done with buf cur
    }

    // epilogue: O^T rows hd=16mf+4lq+r, col q=16qh+l15 -> attnout [B][S][H*HD]
    #pragma unroll
    for (int qh = 0; qh < 2; qh++) {
      float lr = lpart[qh];
      lr += __shfl_xor(lr, 16);
      lr += __shfl_xor(lr, 32);
      const float rinv = __builtin_amdgcn_rcpf(lr);
      const int q = qw + qh * 16 + l15;
      #pragma unroll
      for (int mf = 0; mf < 4; mf++) {
        const f32x4 o = oacc[mf][qh];
        const uint2 u = make_uint2(cvtpk(o[0] * rinv, o[1] * rinv),
                                   cvtpk(o[2] * rinv, o[3] * rinv));
        *(uint2*)(attnout + ((size_t)b * S_ + q) * (H_ * HD_) + h * 64 + mf * 16 + lq * 4) = u;
      }
    }
  }
}

extern "C" void kernel_launch(void* const* d_in, const int* in_sizes, int n_in,
                              void* d_out, int out_size, void* d_ws, size_t ws_size,
                              hipStream_t stream) {
  const float* query = (const float*)d_in[0];
  const float* key_  = (const float*)d_in[1];
  const float* value = (const float*)d_in[2];
  // d_in[3] = causal mask — implied analytically
  const float* Wq = (const float*)d_in[4];
  const float* Wk = (const float*)d_in[5];
  const float* Wv = (const float*)d_in[6];
  const float* Wo = (const float*)d_in[7];
  const float* bo = (const float*)d_in[8];
  float* out = (float*)d_out;

  char* ws = (char*)d_ws;
  const size_t MB = (size_t)1 << 20;
  short* Xbuf = (short*)(ws);             // 16 MB: attn output
  short* Wqt  = (short*)(ws + 16 * MB);
  short* Wkt  = (short*)(ws + 18 * MB);
  short* Wvt  = (short*)(ws + 20 * MB);
  short* Wot  = (short*)(ws + 22 * MB);
  short* Qh   = (short*)(ws + 24 * MB);   // 16 MB [B][H][S][HD], pre-scaled by 0.125*log2e
  short* Kh   = (short*)(ws + 40 * MB);   // 16 MB [B][H][S][HD]
  short* Vt   = (short*)(ws + 56 * MB);   // 16 MB [B][H][HD][S]   (total 72 MB)

  const dim3 tb(32, 8);
  const dim3 tg4(32, 32, 4);
  const float QSCALE = 0.125f * 1.4426950408889634f;  // fold 1/sqrt(HD) * log2(e) into Q

  transpose_cast_w4<<<tg4, tb, 0, stream>>>(Wq, Wk, Wv, Wo, Wqt, Wkt, Wvt, Wot);

  gemm_qkv<<<dim3(8, 64, 3), 256, 0, stream>>>(query, key_, value, Wqt, Wkt, Wvt,
                                               Qh, Kh, Vt, QSCALE);

  attn_kernel<<<dim3(512), 256, 0, stream>>>(Qh, Kh, Vt, Xbuf);

  gemm_o<<<dim3(8, 64), 256, 0, stream>>>(Xbuf, Wot, out, bo);
}